// Round 7
// baseline (139.182 us; speedup 1.0000x reference)
//
#include <hip/hip_runtime.h>
#include <hip/hip_bf16.h>
#include <math.h>

// Problem dims
#define VOCAB 400000
#define D     300
#define L     2000
#define B     4
#define C1    64
#define C2    128
#define K2    500
#define HID   256
#define NCLS  5
#define NP1   1999   // pooled length after conv1+pool(300)
#define T2    1500   // conv2 out length
#define TPAD  2304   // padded t-length (B staging reads up to t0max+768 = 2112)
#define S     8      // cin split groups (8 cin each)
#define CI    8      // cin per group
#define NK2   125    // MFMA K-steps: k = 4*k2 + g, K=32 per step
#define BN    192    // t per block tile
#define NTI   8      // t tiles (8*192 = 1536 >= 1500)
#define NKT   1600   // weight-transpose blocks: 8 s * 25 kc * 8 cog

typedef __attribute__((ext_vector_type(8))) short short8v;
typedef __attribute__((ext_vector_type(4))) float f32x4;

__device__ __forceinline__ void gload_lds16(const void* g, void* l) {
    __builtin_amdgcn_global_load_lds(
        (const __attribute__((address_space(1))) void*)g,
        (__attribute__((address_space(3))) void*)l, 16, 0, 0);
}

// ---------------------------------------------------------------------------
// k_prep: fused [weight transpose] + [embed+conv1+relu+pool].
// Blocks [0,1600): aT[s][k2][g][co][e] = w2[co][s*8+e][4*k2+g]  (bf16)
// Blocks [1600,1600+7996): in1T[b][sg][t][ci] = relu(maxpool(conv1(emb)))
// ---------------------------------------------------------------------------
__global__ __launch_bounds__(256) void k_prep(
    const int* __restrict__ x, const float* __restrict__ emb,
    const float* __restrict__ w1, const float* __restrict__ b1,
    const float* __restrict__ w2,
    __hip_bfloat16* __restrict__ in1T, __hip_bfloat16* __restrict__ aT)
{
    __shared__ float smem[2560];   // kT tile: 16co x 8ci x 20k ; k1: sig+red
    int bid = blockIdx.x, tid = threadIdx.x;
    if (bid < NKT) {
        // ---- weight transpose: s(8) x kc(25, 5 k2 each = 20 k) x cog(8, 16 co)
        int s  = bid / 200;
        int rem = bid % 200;
        int kc = rem / 8, cog = rem % 8;
        int co0 = cog * 16;
        for (int i = tid; i < 2560; i += 256) {
            int co_l = i / 160, r = i % 160, ci = r / 20, kl = r % 20;
            smem[i] = w2[((size_t)(co0 + co_l) * C1 + s * CI + ci) * K2 + kc * 20 + kl];
        }
        __syncthreads();
        for (int u = tid; u < 320; u += 256) {
            int co_l = u & 15, gk = u >> 4;      // gk 0..19
            int g = gk & 3, k2l = gk >> 2;       // k2l 0..4
            __hip_bfloat16 tmp[8];
#pragma unroll
            for (int e = 0; e < 8; ++e)
                tmp[e] = __float2bfloat16(smem[co_l * 160 + e * 20 + 4 * k2l + g]);
            size_t off = ((size_t)((s * NK2 + kc * 5 + k2l) * 4 + g)) * 1024
                       + (size_t)(co0 + co_l) * 8;
            *reinterpret_cast<int4*>(aT + off) = *reinterpret_cast<const int4*>(tmp);
        }
    } else {
        // ---- embed + conv1 + relu + maxpool(300)
        int blk = bid - NKT;
        int b = blk / NP1, p = blk % NP1;
        float* sig = smem;           // 304 floats
        float* red = smem + 304;     // 4 x 64
        int row0 = x[b * L + p];
        int row1 = x[b * L + p + 1];
        if (tid < 76) {
            const float* src = (tid < 75) ? (emb + (size_t)row0 * D + 4 * tid)
                                          : (emb + (size_t)row1 * D);
            *reinterpret_cast<float4*>(sig + 4 * tid) =
                *reinterpret_cast<const float4*>(src);
        }
        __syncthreads();
        int c = tid & 63, g = tid >> 6;
        float wa = w1[c * 3 + 0], wb = w1[c * 3 + 1], wc = w1[c * 3 + 2];
        float bb = b1[c];
        int jb = 76 * g;
        int ns = (g < 3) ? 19 : 18;              // g=3 covers j 228..299
        float m = -INFINITY;
        float4 cur = *reinterpret_cast<float4*>(sig + jb);   // broadcast reads
        for (int st = 0; st < ns; ++st) {
            float4 nxt = *reinterpret_cast<float4*>(sig + jb + 4 * st + 4);
            float xx[8] = {cur.x, cur.y, cur.z, cur.w, nxt.x, nxt.y, nxt.z, nxt.w};
#pragma unroll
            for (int q = 0; q < 4; ++q) {
                float v = fmaf(wc, xx[q + 2], fmaf(wb, xx[q + 1], fmaf(wa, xx[q], bb)));
                m = fmaxf(m, v);
            }
            cur = nxt;
        }
        red[g * 64 + c] = m;
        __syncthreads();
        if (tid < 64) {
            float mm = fmaxf(fmaxf(red[tid], red[64 + tid]),
                             fmaxf(red[128 + tid], red[192 + tid]));
            int sg = tid >> 3, ci = tid & 7;
            in1T[((size_t)(b * S + sg) * TPAD + p) * CI + ci] =
                __float2bfloat16(fmaxf(mm, 0.0f));
        }
    }
}

// ---------------------------------------------------------------------------
// k2_mfma: conv2 as bf16 MFMA GEMM, cin split 8 ways. (R5 structure)
// grid 256 = 8s x 4b x 8ti, 1 block/CU. s = bid&7 matches XCD round-robin.
// Block: 128co x 192t, 4 waves (2co x 2t) of 64co x 96t, 24 mfma/K-step.
// B staged in LDS once; A 2-deep register prefetch; no barriers in loop.
// ---------------------------------------------------------------------------
__global__ __launch_bounds__(256, 1) void k2_mfma(
    const __hip_bfloat16* __restrict__ in1T,
    const __hip_bfloat16* __restrict__ aT,
    float* __restrict__ part)
{
    int bid = blockIdx.x;
    int s = bid & 7;                 // matches XCD round-robin
    int rem = bid >> 3;              // 0..31
    int b = rem >> 3, ti = rem & 7;
    int t0 = ti * BN;

    __shared__ __align__(16) __hip_bfloat16 seg[768 * CI];    // 12288 B

    int tid = threadIdx.x;
    int w = tid >> 6, l = tid & 63;
    int lane16 = l & 15, g = l >> 4;
    int co0w = (w & 1) * 64;         // wave co base (2 co-waves)
    int tn0  = (w >> 1) * 96;        // wave t base  (2 t-waves)

    // stage B once: 768 rows x 16 B, contiguous (in1T[b][s][t][ci])
    {
        const char* gsrc = (const char*)(in1T + ((size_t)(b * S + s) * TPAD + t0) * CI);
        char* lb = (char*)seg + w * 1024;
#pragma unroll
        for (int r = 0; r < 3; ++r)
            gload_lds16(gsrc + (size_t)(r * 256 + tid) * 16, lb + r * 4096);
    }
    __syncthreads();   // drains vmcnt(0): B fully in LDS; only barrier needed

    // per-lane A base: aT[s][k2][g][co][e], frag fa covers co0w+fa*16..+15
    const __hip_bfloat16* abase =
        aT + (size_t)s * NK2 * 4096 + g * 1024 + (co0w + lane16) * 8;

    f32x4 acc[4][6];
#pragma unroll
    for (int fa = 0; fa < 4; ++fa)
#pragma unroll
        for (int fb = 0; fb < 6; ++fb) acc[fa][fb] = (f32x4){0.f, 0.f, 0.f, 0.f};

#define LOADA(AR, KK)                                                         \
    {                                                                         \
        _Pragma("unroll")                                                     \
        for (int fa = 0; fa < 4; ++fa)                                        \
            AR[fa] = *reinterpret_cast<const short8v*>(                       \
                abase + (size_t)(KK) * 4096 + fa * 128);                      \
    }

#define STEP(AR, KK)                                                          \
    {                                                                         \
        short8v bfr[6];                                                       \
        _Pragma("unroll")                                                     \
        for (int fb = 0; fb < 6; ++fb)                                        \
            bfr[fb] = *reinterpret_cast<const short8v*>(                      \
                seg + (size_t)(tn0 + fb * 16 + lane16 + 4 * (KK) + g) * 8);   \
        _Pragma("unroll")                                                     \
        for (int fa = 0; fa < 4; ++fa) {                                      \
            _Pragma("unroll")                                                 \
            for (int fb = 0; fb < 6; ++fb)                                    \
                acc[fa][fb] = __builtin_amdgcn_mfma_f32_16x16x32_bf16(        \
                    AR[fa], bfr[fb], acc[fa][fb], 0, 0, 0);                   \
        }                                                                     \
    }

    short8v a0[4], a1[4];
    LOADA(a0, 0);
    LOADA(a1, 1);
    int k2 = 0;
#pragma unroll 1
    for (; k2 + 3 < NK2; k2 += 2) {      // k2 = 0,2,...,120; exits k2 = 122
        STEP(a0, k2);
        LOADA(a0, k2 + 2);
        STEP(a1, k2 + 1);
        LOADA(a1, k2 + 3);
    }
    STEP(a0, k2);          // 122
    LOADA(a0, k2 + 2);
    STEP(a1, k2 + 1);      // 123
    STEP(a0, k2 + 2);      // 124

#undef LOADA
#undef STEP

    // epilogue: C/D layout col=lane16 (t), row=4*g+r (co within 16)
#pragma unroll
    for (int fa = 0; fa < 4; ++fa) {
#pragma unroll
        for (int fb = 0; fb < 6; ++fb) {
            int t = t0 + tn0 + fb * 16 + lane16;
            if (t < T2) {
                int cob = co0w + fa * 16 + 4 * g;
#pragma unroll
                for (int r = 0; r < 4; ++r)
                    part[((size_t)(s * B + b) * C2 + cob + r) * T2 + t] =
                        acc[fa][fb][r];
            }
        }
    }
}

// ---------------------------------------------------------------------------
// k2b: sum 8 cin-group partials + bias, relu + maxpool(1500) -> h1[b][co]
// ---------------------------------------------------------------------------
__global__ __launch_bounds__(256) void k2b_pool(
    const float* __restrict__ part, const float* __restrict__ b2,
    float* __restrict__ h1)
{
    int bc = blockIdx.x;             // b*C2 + co
    int b = bc / C2, co = bc % C2;
    int tid = threadIdx.x;
    float m = -INFINITY;
    for (int t4 = tid; t4 < T2 / 4; t4 += 256) {
        float4 sum = {0.f, 0.f, 0.f, 0.f};
#pragma unroll
        for (int s = 0; s < S; ++s) {
            const float4* p = reinterpret_cast<const float4*>(
                part + ((size_t)(s * B + b) * C2 + co) * T2);
            float4 v = p[t4];
            sum.x += v.x; sum.y += v.y; sum.z += v.z; sum.w += v.w;
        }
        m = fmaxf(m, fmaxf(fmaxf(sum.x, sum.y), fmaxf(sum.z, sum.w)));
    }
    __shared__ float red[256];
    red[tid] = m;
    __syncthreads();
    for (int st = 128; st > 0; st >>= 1) {
        if (tid < st) red[tid] = fmaxf(red[tid], red[tid + st]);
        __syncthreads();
    }
    if (tid == 0) h1[bc] = fmaxf(red[0] + b2[co], 0.0f);
}

// ---------------------------------------------------------------------------
// k3: lin1 + relu + lin2 + softmax. One block per batch row.
// ---------------------------------------------------------------------------
__global__ __launch_bounds__(256) void k3_head(
    const float* __restrict__ h1,
    const float* __restrict__ wl1, const float* __restrict__ bl1,
    const float* __restrict__ wl2, const float* __restrict__ bl2,
    float* __restrict__ out)
{
    int b = blockIdx.x;
    int tid = threadIdx.x;
    __shared__ float xin[C2];
    __shared__ float hbuf[HID];
    __shared__ float lg[NCLS];
    if (tid < C2) xin[tid] = h1[b * C2 + tid];
    __syncthreads();
    float a = bl1[tid];
    for (int c = 0; c < C2; ++c) a = fmaf(xin[c], wl1[tid * C2 + c], a);
    hbuf[tid] = fmaxf(a, 0.0f);
    __syncthreads();
    if (tid < NCLS) {
        float lv = bl2[tid];
        for (int j = 0; j < HID; ++j) lv = fmaf(hbuf[j], wl2[tid * HID + j], lv);
        lg[tid] = lv;
    }
    __syncthreads();
    if (tid < NCLS) {
        float mx = lg[0];
        for (int i = 1; i < NCLS; ++i) mx = fmaxf(mx, lg[i]);
        float sum = 0.f;
        for (int i = 0; i < NCLS; ++i) sum += expf(lg[i] - mx);
        out[b * NCLS + tid] = expf(lg[tid] - mx) / sum;
    }
}

extern "C" void kernel_launch(void* const* d_in, const int* in_sizes, int n_in,
                              void* d_out, int out_size, void* d_ws, size_t ws_size,
                              hipStream_t stream)
{
    const int*   x   = (const int*)  d_in[0];
    const float* emb = (const float*)d_in[1];
    const float* w1  = (const float*)d_in[2];
    const float* b1  = (const float*)d_in[3];
    const float* w2  = (const float*)d_in[4];
    const float* b2  = (const float*)d_in[5];
    const float* wl1 = (const float*)d_in[6];
    const float* bl1 = (const float*)d_in[7];
    const float* wl2 = (const float*)d_in[8];
    const float* bl2 = (const float*)d_in[9];
    float* out = (float*)d_out;

    // workspace (floats): part 8*4*128*1500 = 6,144,000 | h1 512 |
    // in1T 4*8*2304*8 bf16 = 589824 | aT 8*125*4096 bf16 = 4,096,000
    float* ws   = (float*)d_ws;
    float* part = ws;
    float* h1   = ws + (size_t)S * B * C2 * T2;
    __hip_bfloat16* in1T = (__hip_bfloat16*)(h1 + 512);
    __hip_bfloat16* aT   = in1T + (size_t)B * S * TPAD * CI;

    hipLaunchKernelGGL(k_prep, dim3(NKT + B * NP1), dim3(256), 0, stream,
                       x, emb, w1, b1, w2, in1T, aT);
    // MEASUREMENT ROUND: k2_mfma launched TWICE (idempotent — identical inputs
    // and outputs; second overwrites part with the same values). The dur_us
    // delta vs Round 5 (92.8 us) isolates k2_mfma's true duration, since the
    // harness's fill kernels occlude rocprof's top-5.
    hipLaunchKernelGGL(k2_mfma, dim3(256), dim3(256), 0, stream, in1T, aT, part);
    hipLaunchKernelGGL(k2_mfma, dim3(256), dim3(256), 0, stream, in1T, aT, part);
    hipLaunchKernelGGL(k2b_pool, dim3(B * C2), dim3(256), 0, stream, part, b2, h1);
    hipLaunchKernelGGL(k3_head, dim3(B), dim3(256), 0, stream,
                       h1, wl1, bl1, wl2, bl2, out);
}

// Round 8
// 82.758 us; speedup vs baseline: 1.6818x; 1.6818x over previous
//
#include <hip/hip_runtime.h>
#include <hip/hip_bf16.h>
#include <math.h>

// Problem dims
#define VOCAB 400000
#define D     300
#define L     2000
#define B     4
#define C1    64
#define C2    128
#define K2    500
#define HID   256
#define NCLS  5
#define NP1   1999   // pooled length after conv1+pool(300)
#define T2    1500   // conv2 out length
#define TPAD  2304   // padded t-length (B staging reads up to t0max+768 = 2112)
#define S     8      // cin split groups (8 cin each)
#define CI    8      // cin per group
#define NK2   125    // MFMA K-steps: k = 4*k2 + g, K=32 per step
#define BN    192    // t per block tile
#define NKT   1600   // weight-transpose blocks: 8 s * 25 kc * 8 cog
#define NC1B  (B * 500)  // conv1 blocks, 4 windows each

typedef __attribute__((ext_vector_type(8))) short short8v;
typedef __attribute__((ext_vector_type(4))) float f32x4;

__device__ __forceinline__ void gload_lds16(const void* g, void* l) {
    __builtin_amdgcn_global_load_lds(
        (const __attribute__((address_space(1))) void*)g,
        (__attribute__((address_space(3))) void*)l, 16, 0, 0);
}

// ---------------------------------------------------------------------------
// k_prep: fused [weight transpose] + [embed+conv1+relu+pool].
// Blocks [0,1600): aT[s][k2][g][co][e] = w2[co][s*8+e][4*k2+g]  (bf16)
// Blocks [1600,1600+2000): 4 pool-windows per block:
//   in1T[b][sg][p][ci] = relu(maxpool300(conv1(emb gather)))
// ---------------------------------------------------------------------------
__global__ __launch_bounds__(256) void k_prep(
    const int* __restrict__ x, const float* __restrict__ emb,
    const float* __restrict__ w1, const float* __restrict__ b1,
    const float* __restrict__ w2,
    __hip_bfloat16* __restrict__ in1T, __hip_bfloat16* __restrict__ aT)
{
    __shared__ float smem[2560];   // kT tile 2560; conv1 sig 1204
    int bid = blockIdx.x, tid = threadIdx.x;
    if (bid < NKT) {
        // ---- weight transpose: s(8) x kc(25, 5 k2 each = 20 k) x cog(8, 16 co)
        int s  = bid / 200;
        int rem = bid % 200;
        int kc = rem / 8, cog = rem % 8;
        int co0 = cog * 16;
        for (int i = tid; i < 2560; i += 256) {
            int co_l = i / 160, r = i % 160, ci = r / 20, kl = r % 20;
            smem[i] = w2[((size_t)(co0 + co_l) * C1 + s * CI + ci) * K2 + kc * 20 + kl];
        }
        __syncthreads();
        for (int u = tid; u < 320; u += 256) {
            int co_l = u & 15, gk = u >> 4;      // gk 0..19
            int g = gk & 3, k2l = gk >> 2;       // k2l 0..4
            __hip_bfloat16 tmp[8];
#pragma unroll
            for (int e = 0; e < 8; ++e)
                tmp[e] = __float2bfloat16(smem[co_l * 160 + e * 20 + 4 * k2l + g]);
            size_t off = ((size_t)((s * NK2 + kc * 5 + k2l) * 4 + g)) * 1024
                       + (size_t)(co0 + co_l) * 8;
            *reinterpret_cast<int4*>(aT + off) = *reinterpret_cast<const int4*>(tmp);
        }
    } else {
        // ---- embed + conv1 + relu + maxpool(300), 4 windows per block
        int blk = bid - NKT;
        int b = blk / 500, pb = blk % 500;
        int p0 = pb * 4;
        float* sig = smem;           // 1204 floats: rows p0..p0+4 x 300 cols
        if (tid < 301) {
            int rj = tid / 75, col = (tid % 75) * 4;
            int xi = p0 + rj; if (xi > L - 1) xi = L - 1;     // clamp (guarded use)
            int row = x[b * L + xi];
            *reinterpret_cast<float4*>(sig + 4 * tid) =
                *reinterpret_cast<const float4*>(emb + (size_t)row * D + col);
        }
        __syncthreads();
        int c = tid & 63, pg = tid >> 6;
        int p = p0 + pg;
        float wa = w1[c * 3 + 0], wb = w1[c * 3 + 1], wc = w1[c * 3 + 2];
        float bb = b1[c];
        int jb = 300 * pg;
        float m = -INFINITY;
        float4 cur = *reinterpret_cast<float4*>(sig + jb);   // broadcast reads
        for (int st = 0; st < 75; ++st) {
            float4 nxt = *reinterpret_cast<float4*>(sig + jb + 4 * st + 4);
            float xx[8] = {cur.x, cur.y, cur.z, cur.w, nxt.x, nxt.y, nxt.z, nxt.w};
#pragma unroll
            for (int q = 0; q < 4; ++q) {
                float v = fmaf(wc, xx[q + 2], fmaf(wb, xx[q + 1], fmaf(wa, xx[q], bb)));
                m = fmaxf(m, v);
            }
            cur = nxt;
        }
        if (p < NP1) {
            int sg = c >> 3, ci = c & 7;
            in1T[((size_t)(b * S + sg) * TPAD + p) * CI + ci] =
                __float2bfloat16(fmaxf(m, 0.0f));
        }
    }
}

// ---------------------------------------------------------------------------
// k2_mfma: conv2 as bf16 MFMA GEMM, cin split 8 ways.
// grid 256 = 8s x 4b x 8ti, 1 block/CU, but 512 threads = 8 waves =
// 2 waves/SIMD (TLP hides lgkm/vmem stalls that the 4-wave version exposed).
// Block: 128co x 192t; wave tile 64co x 48t (acc 48 VGPR).
// B staged in LDS once; A 2-deep register prefetch; no barriers in loop.
// ---------------------------------------------------------------------------
__global__ __launch_bounds__(512, 1) void k2_mfma(
    const __hip_bfloat16* __restrict__ in1T,
    const __hip_bfloat16* __restrict__ aT,
    float* __restrict__ part)
{
    int bid = blockIdx.x;
    int s = bid & 7;                 // matches XCD round-robin
    int rem = bid >> 3;              // 0..31
    int b = rem >> 3, ti = rem & 7;
    int t0 = ti * BN;

    __shared__ __align__(16) __hip_bfloat16 seg[768 * CI];    // 12288 B

    int tid = threadIdx.x;
    int w = tid >> 6, l = tid & 63;  // 8 waves
    int lane16 = l & 15, g = l >> 4;
    int co0w = (w & 1) * 64;         // 2 co-halves
    int tn0  = (w >> 1) * 48;        // 4 t-quarters

    // stage B once: 768 rows x 16 B, contiguous (in1T[b][s][t][ci])
    {
        const char* gsrc = (const char*)(in1T + ((size_t)(b * S + s) * TPAD + t0) * CI);
        char* lb = (char*)seg + w * 1024;
        gload_lds16(gsrc + (size_t)tid * 16, lb);             // rows 0..511
        if (tid < 256)                                        // waves 0..3
            gload_lds16(gsrc + (size_t)(512 + tid) * 16, lb + 8192);
    }
    __syncthreads();   // drains vmcnt(0): B fully in LDS; only barrier needed

    // per-lane A base: aT[s][k2][g][co][e], frag fa covers co0w+fa*16..+15
    const __hip_bfloat16* abase =
        aT + (size_t)s * NK2 * 4096 + g * 1024 + (co0w + lane16) * 8;

    f32x4 acc[4][3];
#pragma unroll
    for (int fa = 0; fa < 4; ++fa)
#pragma unroll
        for (int fb = 0; fb < 3; ++fb) acc[fa][fb] = (f32x4){0.f, 0.f, 0.f, 0.f};

#define LOADA(AR, KK)                                                         \
    {                                                                         \
        _Pragma("unroll")                                                     \
        for (int fa = 0; fa < 4; ++fa)                                        \
            AR[fa] = *reinterpret_cast<const short8v*>(                       \
                abase + (size_t)(KK) * 4096 + fa * 128);                      \
    }

#define STEP(AR, KK)                                                          \
    {                                                                         \
        short8v bfr[3];                                                       \
        _Pragma("unroll")                                                     \
        for (int fb = 0; fb < 3; ++fb)                                        \
            bfr[fb] = *reinterpret_cast<const short8v*>(                      \
                seg + (size_t)(tn0 + fb * 16 + lane16 + 4 * (KK) + g) * 8);   \
        _Pragma("unroll")                                                     \
        for (int fa = 0; fa < 4; ++fa) {                                      \
            _Pragma("unroll")                                                 \
            for (int fb = 0; fb < 3; ++fb)                                    \
                acc[fa][fb] = __builtin_amdgcn_mfma_f32_16x16x32_bf16(        \
                    AR[fa], bfr[fb], acc[fa][fb], 0, 0, 0);                   \
        }                                                                     \
    }

    short8v a0[4], a1[4];
    LOADA(a0, 0);
    LOADA(a1, 1);
    int k2 = 0;
#pragma unroll 1
    for (; k2 + 3 < NK2; k2 += 2) {      // k2 = 0,2,...,120; exits k2 = 122
        STEP(a0, k2);
        LOADA(a0, k2 + 2);
        STEP(a1, k2 + 1);
        LOADA(a1, k2 + 3);
    }
    STEP(a0, k2);          // 122
    LOADA(a0, k2 + 2);
    STEP(a1, k2 + 1);      // 123
    STEP(a0, k2 + 2);      // 124

#undef LOADA
#undef STEP

    // epilogue: C/D layout col=lane16 (t), row=4*g+r (co within 16)
#pragma unroll
    for (int fa = 0; fa < 4; ++fa) {
#pragma unroll
        for (int fb = 0; fb < 3; ++fb) {
            int t = t0 + tn0 + fb * 16 + lane16;
            if (t < T2) {
                int cob = co0w + fa * 16 + 4 * g;
#pragma unroll
                for (int r = 0; r < 4; ++r)
                    part[((size_t)(s * B + b) * C2 + cob + r) * T2 + t] =
                        acc[fa][fb][r];
            }
        }
    }
}

// ---------------------------------------------------------------------------
// k2b: sum 8 cin-group partials + bias, relu + maxpool(1500) -> h1[b][co]
// ---------------------------------------------------------------------------
__global__ __launch_bounds__(256) void k2b_pool(
    const float* __restrict__ part, const float* __restrict__ b2,
    float* __restrict__ h1)
{
    int bc = blockIdx.x;             // b*C2 + co
    int b = bc / C2, co = bc % C2;
    int tid = threadIdx.x;
    float m = -INFINITY;
    for (int t4 = tid; t4 < T2 / 4; t4 += 256) {
        float4 sum = {0.f, 0.f, 0.f, 0.f};
#pragma unroll
        for (int s = 0; s < S; ++s) {
            const float4* p = reinterpret_cast<const float4*>(
                part + ((size_t)(s * B + b) * C2 + co) * T2);
            float4 v = p[t4];
            sum.x += v.x; sum.y += v.y; sum.z += v.z; sum.w += v.w;
        }
        m = fmaxf(m, fmaxf(fmaxf(sum.x, sum.y), fmaxf(sum.z, sum.w)));
    }
    __shared__ float red[256];
    red[tid] = m;
    __syncthreads();
    for (int st = 128; st > 0; st >>= 1) {
        if (tid < st) red[tid] = fmaxf(red[tid], red[tid + st]);
        __syncthreads();
    }
    if (tid == 0) h1[bc] = fmaxf(red[0] + b2[co], 0.0f);
}

// ---------------------------------------------------------------------------
// k3: lin1 + relu + lin2 + softmax. One block per batch row.
// ---------------------------------------------------------------------------
__global__ __launch_bounds__(256) void k3_head(
    const float* __restrict__ h1,
    const float* __restrict__ wl1, const float* __restrict__ bl1,
    const float* __restrict__ wl2, const float* __restrict__ bl2,
    float* __restrict__ out)
{
    int b = blockIdx.x;
    int tid = threadIdx.x;
    __shared__ float xin[C2];
    __shared__ float hbuf[HID];
    __shared__ float lg[NCLS];
    if (tid < C2) xin[tid] = h1[b * C2 + tid];
    __syncthreads();
    float a = bl1[tid];
    for (int c = 0; c < C2; ++c) a = fmaf(xin[c], wl1[tid * C2 + c], a);
    hbuf[tid] = fmaxf(a, 0.0f);
    __syncthreads();
    if (tid < NCLS) {
        float lv = bl2[tid];
        for (int j = 0; j < HID; ++j) lv = fmaf(hbuf[j], wl2[tid * HID + j], lv);
        lg[tid] = lv;
    }
    __syncthreads();
    if (tid < NCLS) {
        float mx = lg[0];
        for (int i = 1; i < NCLS; ++i) mx = fmaxf(mx, lg[i]);
        float sum = 0.f;
        for (int i = 0; i < NCLS; ++i) sum += expf(lg[i] - mx);
        out[b * NCLS + tid] = expf(lg[tid] - mx) / sum;
    }
}

extern "C" void kernel_launch(void* const* d_in, const int* in_sizes, int n_in,
                              void* d_out, int out_size, void* d_ws, size_t ws_size,
                              hipStream_t stream)
{
    const int*   x   = (const int*)  d_in[0];
    const float* emb = (const float*)d_in[1];
    const float* w1  = (const float*)d_in[2];
    const float* b1  = (const float*)d_in[3];
    const float* w2  = (const float*)d_in[4];
    const float* b2  = (const float*)d_in[5];
    const float* wl1 = (const float*)d_in[6];
    const float* bl1 = (const float*)d_in[7];
    const float* wl2 = (const float*)d_in[8];
    const float* bl2 = (const float*)d_in[9];
    float* out = (float*)d_out;

    // workspace (floats): part 8*4*128*1500 = 6,144,000 | h1 512 |
    // in1T 4*8*2304*8 bf16 = 589824 | aT 8*125*4096 bf16 = 4,096,000
    float* ws   = (float*)d_ws;
    float* part = ws;
    float* h1   = ws + (size_t)S * B * C2 * T2;
    __hip_bfloat16* in1T = (__hip_bfloat16*)(h1 + 512);
    __hip_bfloat16* aT   = in1T + (size_t)B * S * TPAD * CI;

    hipLaunchKernelGGL(k_prep, dim3(NKT + NC1B), dim3(256), 0, stream,
                       x, emb, w1, b1, w2, in1T, aT);
    hipLaunchKernelGGL(k2_mfma, dim3(256), dim3(512), 0, stream, in1T, aT, part);
    hipLaunchKernelGGL(k2b_pool, dim3(B * C2), dim3(256), 0, stream, part, b2, h1);
    hipLaunchKernelGGL(k3_head, dim3(B), dim3(256), 0, stream,
                       h1, wl1, bl1, wl2, bl2, out);
}

// Round 9
// 78.776 us; speedup vs baseline: 1.7668x; 1.0506x over previous
//
#include <hip/hip_runtime.h>
#include <hip/hip_bf16.h>
#include <math.h>

// Problem dims
#define VOCAB 400000
#define D     300
#define L     2000
#define B     4
#define C1    64
#define C2    128
#define K2    500
#define HID   256
#define NCLS  5
#define NP1   1999   // pooled length after conv1+pool(300)
#define T2    1500   // conv2 out length
#define TPAD  2304   // padded t-length (staging reads up to t0max+639 = 2079)
#define S     8      // cin split groups (8 cin each)
#define CI    8      // cin per group
#define NK2   125    // MFMA K-steps: k = 4*k2 + g, K=32 per step
#define BN    96     // t per block tile
#define SEGR  640    // staged B rows per block (t0..t0+639; reads need <= 594)
#define NWT   128    // weight-transpose blocks: 8 s * 16 cog(8 co each)
#define NC1B  (B * 500)  // conv1 blocks, 4 windows each

typedef __attribute__((ext_vector_type(8))) short short8v;
typedef __attribute__((ext_vector_type(4))) float f32x4;

__device__ __forceinline__ void gload_lds16(const void* g, void* l) {
    __builtin_amdgcn_global_load_lds(
        (const __attribute__((address_space(1))) void*)g,
        (__attribute__((address_space(3))) void*)l, 16, 0, 0);
}

// ---------------------------------------------------------------------------
// k_prep: fused [weight transpose (LDS-free)] + [embed+conv1+relu+pool].
// Blocks [0,128): aT[s][k2][g][co][e] = w2[co][s*8+e][4*k2+g]  (bf16)
//   block = (s, cog of 8 co); 4000 int4 outputs per block, direct from L1/L2.
// Blocks [128,128+2000): 4 pool-windows per block:
//   in1T[b][sg][p][ci] = relu(maxpool300(conv1(emb gather)))
// ---------------------------------------------------------------------------
__global__ __launch_bounds__(256) void k_prep(
    const int* __restrict__ x, const float* __restrict__ emb,
    const float* __restrict__ w1, const float* __restrict__ b1,
    const float* __restrict__ w2,
    __hip_bfloat16* __restrict__ in1T, __hip_bfloat16* __restrict__ aT)
{
    __shared__ float smem[1204];
    int bid = blockIdx.x, tid = threadIdx.x;
    if (bid < NWT) {
        // ---- weight transpose: s(8) x cog(16, 8 co each)
        int s = bid >> 4, cog = bid & 15;
        for (int u = tid; u < 4000; u += 256) {
            int co_l = u & 7, kg = u >> 3;       // kg = k2*4+g, 0..499
            int k2 = kg >> 2, g = kg & 3;
            int co = cog * 8 + co_l;
            __hip_bfloat16 tmp[8];
#pragma unroll
            for (int e = 0; e < 8; ++e)
                tmp[e] = __float2bfloat16(
                    w2[((size_t)co * C1 + s * CI + e) * K2 + 4 * k2 + g]);
            *reinterpret_cast<int4*>(
                aT + ((size_t)((s * NK2 + k2) * 4 + g)) * 1024 + (size_t)co * 8) =
                *reinterpret_cast<const int4*>(tmp);
        }
    } else {
        // ---- embed + conv1 + relu + maxpool(300), 4 windows per block
        int blk = bid - NWT;
        int b = blk / 500, pb = blk % 500;
        int p0 = pb * 4;
        float* sig = smem;           // 1204 floats: rows p0..p0+4 x 300 cols
        if (tid < 301) {
            int rj = tid / 75, col = (tid % 75) * 4;
            int xi = p0 + rj; if (xi > L - 1) xi = L - 1;     // clamp (guarded use)
            int row = x[b * L + xi];
            *reinterpret_cast<float4*>(sig + 4 * tid) =
                *reinterpret_cast<const float4*>(emb + (size_t)row * D + col);
        }
        __syncthreads();
        int c = tid & 63, pg = tid >> 6;
        int p = p0 + pg;
        float wa = w1[c * 3 + 0], wb = w1[c * 3 + 1], wc = w1[c * 3 + 2];
        float bb = b1[c];
        int jb = 300 * pg;
        float m = -INFINITY;
        float4 cur = *reinterpret_cast<float4*>(sig + jb);   // broadcast reads
        for (int st = 0; st < 75; ++st) {
            float4 nxt = *reinterpret_cast<float4*>(sig + jb + 4 * st + 4);
            float xx[8] = {cur.x, cur.y, cur.z, cur.w, nxt.x, nxt.y, nxt.z, nxt.w};
#pragma unroll
            for (int q = 0; q < 4; ++q) {
                float v = fmaf(wc, xx[q + 2], fmaf(wb, xx[q + 1], fmaf(wa, xx[q], bb)));
                m = fmaxf(m, v);
            }
            cur = nxt;
        }
        if (p < NP1) {
            int sg = c >> 3, ci = c & 7;
            in1T[((size_t)(b * S + sg) * TPAD + p) * CI + ci] =
                __float2bfloat16(fmaxf(m, 0.0f));
        }
    }
}

// ---------------------------------------------------------------------------
// k2_mfma: conv2 as bf16 MFMA GEMM, cin split 8 ways.
// grid 512 = 8s x 4b x 16ti, 256 threads, 2 BLOCKS/CU (launch_bounds(256,2)).
// The two co-resident blocks are independent (no shared barrier) => their
// LDS-read and MFMA phases interleave instead of phase-locking (the R8
// 8-wave version serialized LDS ~290cyc + MFMA ~466cyc per step).
// Block: 128co x 96t, 4 waves of 64co x 48t, 12 mfma/K-step.
// B staged in LDS once; A 2-deep register prefetch; no barriers in loop.
// ---------------------------------------------------------------------------
__global__ __launch_bounds__(256, 2) void k2_mfma(
    const __hip_bfloat16* __restrict__ in1T,
    const __hip_bfloat16* __restrict__ aT,
    float* __restrict__ part)
{
    int bid = blockIdx.x;
    int s = bid & 7;                 // matches XCD round-robin
    int rem = bid >> 3;              // 0..63
    int b = rem >> 4, ti = rem & 15;
    int t0 = ti * BN;

    __shared__ __align__(16) __hip_bfloat16 seg[SEGR * CI];   // 10240 B

    int tid = threadIdx.x;
    int w = tid >> 6, l = tid & 63;
    int lane16 = l & 15, g = l >> 4;
    int co0w = (w & 1) * 64;         // 2 co-halves
    int tn0  = (w >> 1) * 48;        // 2 t-halves

    // stage B once: 640 rows x 16 B, contiguous (in1T[b][s][t][ci])
    {
        const char* gsrc = (const char*)(in1T + ((size_t)(b * S + s) * TPAD + t0) * CI);
        char* lb = (char*)seg + w * 1024;
        gload_lds16(gsrc + (size_t)tid * 16, lb);                    // rows 0..255
        gload_lds16(gsrc + (size_t)(256 + tid) * 16, lb + 4096);     // 256..511
        if (tid < 128)                                               // waves 0,1 full
            gload_lds16(gsrc + (size_t)(512 + tid) * 16, lb + 8192); // 512..639
    }
    __syncthreads();   // drains vmcnt(0): B fully in LDS; only barrier needed

    // per-lane A base: aT[s][k2][g][co][e], frag fa covers co0w+fa*16..+15
    const __hip_bfloat16* abase =
        aT + (size_t)s * NK2 * 4096 + g * 1024 + (co0w + lane16) * 8;

    f32x4 acc[4][3];
#pragma unroll
    for (int fa = 0; fa < 4; ++fa)
#pragma unroll
        for (int fb = 0; fb < 3; ++fb) acc[fa][fb] = (f32x4){0.f, 0.f, 0.f, 0.f};

#define LOADA(AR, KK)                                                         \
    {                                                                         \
        _Pragma("unroll")                                                     \
        for (int fa = 0; fa < 4; ++fa)                                        \
            AR[fa] = *reinterpret_cast<const short8v*>(                       \
                abase + (size_t)(KK) * 4096 + fa * 128);                      \
    }

#define STEP(AR, KK)                                                         \
    {                                                                         \
        short8v bfr[3];                                                       \
        _Pragma("unroll")                                                     \
        for (int fb = 0; fb < 3; ++fb)                                        \
            bfr[fb] = *reinterpret_cast<const short8v*>(                      \
                seg + (size_t)(tn0 + fb * 16 + lane16 + 4 * (KK) + g) * 8);   \
        _Pragma("unroll")                                                     \
        for (int fa = 0; fa < 4; ++fa) {                                      \
            _Pragma("unroll")                                                 \
            for (int fb = 0; fb < 3; ++fb)                                    \
                acc[fa][fb] = __builtin_amdgcn_mfma_f32_16x16x32_bf16(        \
                    AR[fa], bfr[fb], acc[fa][fb], 0, 0, 0);                   \
        }                                                                     \
    }

    short8v a0[4], a1[4];
    LOADA(a0, 0);
    LOADA(a1, 1);
    int k2 = 0;
#pragma unroll 1
    for (; k2 + 3 < NK2; k2 += 2) {      // k2 = 0,2,...,120; exits k2 = 122
        STEP(a0, k2);
        LOADA(a0, k2 + 2);
        STEP(a1, k2 + 1);
        LOADA(a1, k2 + 3);
    }
    STEP(a0, k2);          // 122
    LOADA(a0, k2 + 2);
    STEP(a1, k2 + 1);      // 123
    STEP(a0, k2 + 2);      // 124

#undef LOADA
#undef STEP

    // epilogue: C/D layout col=lane16 (t), row=4*g+r (co within 16)
#pragma unroll
    for (int fa = 0; fa < 4; ++fa) {
#pragma unroll
        for (int fb = 0; fb < 3; ++fb) {
            int t = t0 + tn0 + fb * 16 + lane16;
            if (t < T2) {
                int cob = co0w + fa * 16 + 4 * g;
#pragma unroll
                for (int r = 0; r < 4; ++r)
                    part[((size_t)(s * B + b) * C2 + cob + r) * T2 + t] =
                        acc[fa][fb][r];
            }
        }
    }
}

// ---------------------------------------------------------------------------
// k2b: sum 8 cin-group partials + bias, relu + maxpool(1500) -> h1[b][co]
// ---------------------------------------------------------------------------
__global__ __launch_bounds__(256) void k2b_pool(
    const float* __restrict__ part, const float* __restrict__ b2,
    float* __restrict__ h1)
{
    int bc = blockIdx.x;             // b*C2 + co
    int b = bc / C2, co = bc % C2;
    int tid = threadIdx.x;
    float m = -INFINITY;
    for (int t4 = tid; t4 < T2 / 4; t4 += 256) {
        float4 sum = {0.f, 0.f, 0.f, 0.f};
#pragma unroll
        for (int s = 0; s < S; ++s) {
            const float4* p = reinterpret_cast<const float4*>(
                part + ((size_t)(s * B + b) * C2 + co) * T2);
            float4 v = p[t4];
            sum.x += v.x; sum.y += v.y; sum.z += v.z; sum.w += v.w;
        }
        m = fmaxf(m, fmaxf(fmaxf(sum.x, sum.y), fmaxf(sum.z, sum.w)));
    }
    __shared__ float red[256];
    red[tid] = m;
    __syncthreads();
    for (int st = 128; st > 0; st >>= 1) {
        if (tid < st) red[tid] = fmaxf(red[tid], red[tid + st]);
        __syncthreads();
    }
    if (tid == 0) h1[bc] = fmaxf(red[0] + b2[co], 0.0f);
}

// ---------------------------------------------------------------------------
// k3: lin1 + relu + lin2 + softmax. One block per batch row.
// ---------------------------------------------------------------------------
__global__ __launch_bounds__(256) void k3_head(
    const float* __restrict__ h1,
    const float* __restrict__ wl1, const float* __restrict__ bl1,
    const float* __restrict__ wl2, const float* __restrict__ bl2,
    float* __restrict__ out)
{
    int b = blockIdx.x;
    int tid = threadIdx.x;
    __shared__ float xin[C2];
    __shared__ float hbuf[HID];
    __shared__ float lg[NCLS];
    if (tid < C2) xin[tid] = h1[b * C2 + tid];
    __syncthreads();
    float a = bl1[tid];
    for (int c = 0; c < C2; ++c) a = fmaf(xin[c], wl1[tid * C2 + c], a);
    hbuf[tid] = fmaxf(a, 0.0f);
    __syncthreads();
    if (tid < NCLS) {
        float lv = bl2[tid];
        for (int j = 0; j < HID; ++j) lv = fmaf(hbuf[j], wl2[tid * HID + j], lv);
        lg[tid] = lv;
    }
    __syncthreads();
    if (tid < NCLS) {
        float mx = lg[0];
        for (int i = 1; i < NCLS; ++i) mx = fmaxf(mx, lg[i]);
        float sum = 0.f;
        for (int i = 0; i < NCLS; ++i) sum += expf(lg[i] - mx);
        out[b * NCLS + tid] = expf(lg[tid] - mx) / sum;
    }
}

extern "C" void kernel_launch(void* const* d_in, const int* in_sizes, int n_in,
                              void* d_out, int out_size, void* d_ws, size_t ws_size,
                              hipStream_t stream)
{
    const int*   x   = (const int*)  d_in[0];
    const float* emb = (const float*)d_in[1];
    const float* w1  = (const float*)d_in[2];
    const float* b1  = (const float*)d_in[3];
    const float* w2  = (const float*)d_in[4];
    const float* b2  = (const float*)d_in[5];
    const float* wl1 = (const float*)d_in[6];
    const float* bl1 = (const float*)d_in[7];
    const float* wl2 = (const float*)d_in[8];
    const float* bl2 = (const float*)d_in[9];
    float* out = (float*)d_out;

    // workspace (floats): part 8*4*128*1500 = 6,144,000 | h1 512 |
    // in1T 4*8*2304*8 bf16 = 589824 | aT 8*125*4096 bf16 = 4,096,000
    float* ws   = (float*)d_ws;
    float* part = ws;
    float* h1   = ws + (size_t)S * B * C2 * T2;
    __hip_bfloat16* in1T = (__hip_bfloat16*)(h1 + 512);
    __hip_bfloat16* aT   = in1T + (size_t)B * S * TPAD * CI;

    hipLaunchKernelGGL(k_prep, dim3(NWT + NC1B), dim3(256), 0, stream,
                       x, emb, w1, b1, w2, in1T, aT);
    hipLaunchKernelGGL(k2_mfma, dim3(512), dim3(256), 0, stream, in1T, aT, part);
    hipLaunchKernelGGL(k2b_pool, dim3(B * C2), dim3(256), 0, stream, part, b2, h1);
    hipLaunchKernelGGL(k3_head, dim3(B), dim3(256), 0, stream,
                       h1, wl1, bl1, wl2, bl2, out);
}

// Round 14
// 78.508 us; speedup vs baseline: 1.7728x; 1.0034x over previous
//
#include <hip/hip_runtime.h>
#include <hip/hip_bf16.h>
#include <math.h>

// Problem dims
#define VOCAB 400000
#define D     300
#define L     2000
#define B     4
#define C1    64
#define C2    128
#define K2    500
#define HID   256
#define NCLS  5
#define NP1   1999   // pooled length after conv1+pool(300)
#define T2    1500   // conv2 out length
#define TPAD  2304   // padded t-length (staging reads up to t0max+639 = 2079)
#define S     8      // cin split groups (8 cin each)
#define CI    8      // cin per group
#define NK2   125    // MFMA K-steps: k = 4*k2 + g, K=32 per step
#define BN    96     // t per block tile
#define SEGR  640    // staged B rows per block (reads need <= 594)
#define NWT   128    // weight-transpose blocks: 8 s * 16 cog(8 co each)
#define NC1B  (B * 500)  // conv1 blocks, 4 windows each

typedef __attribute__((ext_vector_type(8))) short short8v;
typedef __attribute__((ext_vector_type(4))) float f32x4;

__device__ __forceinline__ void gload_lds16(const void* g, void* l) {
    __builtin_amdgcn_global_load_lds(
        (const __attribute__((address_space(1))) void*)g,
        (__attribute__((address_space(3))) void*)l, 16, 0, 0);
}

// ---------------------------------------------------------------------------
// k_prep: fused [weight transpose (LDS-free)] + [embed+conv1+relu+pool].
// BUGFIX (R8-R13 latent): signal staging needs 301 float4s but the old guard
// `if (tid < 301)` with 256 threads wrote only 256 — floats 1024..1203 were
// STALE LDS, corrupting every 4th pooled window nondeterministically (absmax
// 0.0 -> 9.77e-4 at R8; random 0.04-0.79 failures R10-R13). Now a strided loop.
// ---------------------------------------------------------------------------
__global__ __launch_bounds__(256) void k_prep(
    const int* __restrict__ x, const float* __restrict__ emb,
    const float* __restrict__ w1, const float* __restrict__ b1,
    const float* __restrict__ w2,
    __hip_bfloat16* __restrict__ in1T, __hip_bfloat16* __restrict__ aT)
{
    __shared__ float smem[1204];
    int bid = blockIdx.x, tid = threadIdx.x;
    if (bid < NWT) {
        // ---- weight transpose: s(8) x cog(16, 8 co each)
        int s = bid >> 4, cog = bid & 15;
        for (int u = tid; u < 4000; u += 256) {
            int co_l = u & 7, kg = u >> 3;       // kg = k2*4+g, 0..499
            int k2 = kg >> 2, g = kg & 3;
            int co = cog * 8 + co_l;
            __hip_bfloat16 tmp[8];
#pragma unroll
            for (int e = 0; e < 8; ++e)
                tmp[e] = __float2bfloat16(
                    w2[((size_t)co * C1 + s * CI + e) * K2 + 4 * k2 + g]);
            *reinterpret_cast<int4*>(
                aT + ((size_t)((s * NK2 + k2) * 4 + g)) * 1024 + (size_t)co * 8) =
                *reinterpret_cast<const int4*>(tmp);
        }
    } else {
        // ---- embed + conv1 + relu + maxpool(300), 4 windows per block
        int blk = bid - NWT;
        int b = blk / 500, pb = blk % 500;
        int p0 = pb * 4;
        float* sig = smem;           // 1204 floats: rows p0..p0+4 x 300 cols
        for (int i = tid; i < 301; i += 256) {   // BUGFIX: all 301 float4s
            int rj = i / 75, col = (i % 75) * 4;
            int xi = p0 + rj; if (xi > L - 1) xi = L - 1;     // clamp (guarded use)
            int row = x[b * L + xi];
            *reinterpret_cast<float4*>(sig + 4 * i) =
                *reinterpret_cast<const float4*>(emb + (size_t)row * D + col);
        }
        __syncthreads();
        int c = tid & 63, pg = tid >> 6;
        int p = p0 + pg;
        float wa = w1[c * 3 + 0], wb = w1[c * 3 + 1], wc = w1[c * 3 + 2];
        float bb = b1[c];
        int jb = 300 * pg;
        float m = -INFINITY;
        float4 cur = *reinterpret_cast<float4*>(sig + jb);   // broadcast reads
        for (int st = 0; st < 75; ++st) {
            float4 nxt = *reinterpret_cast<float4*>(sig + jb + 4 * st + 4);
            float xx[8] = {cur.x, cur.y, cur.z, cur.w, nxt.x, nxt.y, nxt.z, nxt.w};
#pragma unroll
            for (int q = 0; q < 4; ++q) {
                float v = fmaf(wc, xx[q + 2], fmaf(wb, xx[q + 1], fmaf(wa, xx[q], bb)));
                m = fmaxf(m, v);
            }
            cur = nxt;
        }
        if (p < NP1) {
            int sg = c >> 3, ci = c & 7;
            in1T[((size_t)(b * S + sg) * TPAD + p) * CI + ci] =
                __float2bfloat16(fmaxf(m, 0.0f));
        }
    }
}

// ---------------------------------------------------------------------------
// k2_mfma: conv2 as bf16 MFMA GEMM, cin split 8 ways. (R9-verified structure
// + T5 setprio around the MFMA cluster — pure scheduler hint.)
// grid 512 = 8s x 4b x 16ti, 2 blocks/CU (phase-diverse, no barriers in loop).
// Block: 128co x 96t, 4 waves of 64co x 48t, 12 mfma/K-step.
// B staged in LDS once before the single barrier; A 2-deep register prefetch.
// ---------------------------------------------------------------------------
__global__ __launch_bounds__(256, 2) void k2_mfma(
    const __hip_bfloat16* __restrict__ in1T,
    const __hip_bfloat16* __restrict__ aT,
    float* __restrict__ part)
{
    int bid = blockIdx.x;
    int s = bid & 7;                 // matches XCD round-robin
    int rem = bid >> 3;              // 0..63
    int b = rem >> 4, ti = rem & 15;
    int t0 = ti * BN;

    __shared__ __align__(16) __hip_bfloat16 seg[SEGR * CI];   // 10240 B

    int tid = threadIdx.x;
    int w = tid >> 6, l = tid & 63;
    int lane16 = l & 15, g = l >> 4;
    int co0w = (w & 1) * 64;         // 2 co-halves
    int tn0  = (w >> 1) * 48;        // 2 t-halves

    // stage B once: 640 rows x 16 B, contiguous (in1T[b][s][t][ci])
    {
        const char* gsrc = (const char*)(in1T + ((size_t)(b * S + s) * TPAD + t0) * CI);
        char* lb = (char*)seg + w * 1024;
        gload_lds16(gsrc + (size_t)tid * 16, lb);                    // rows 0..255
        gload_lds16(gsrc + (size_t)(256 + tid) * 16, lb + 4096);     // 256..511
        if (tid < 128)                                               // waves 0,1 full
            gload_lds16(gsrc + (size_t)(512 + tid) * 16, lb + 8192); // 512..639
    }
    __syncthreads();   // drains vmcnt(0): B fully in LDS; only barrier needed

    // per-lane A base: aT[s][k2][g][co][e], frag fa covers co0w+fa*16..+15
    const __hip_bfloat16* abase =
        aT + (size_t)s * NK2 * 4096 + g * 1024 + (co0w + lane16) * 8;

    f32x4 acc[4][3];
#pragma unroll
    for (int fa = 0; fa < 4; ++fa)
#pragma unroll
        for (int fb = 0; fb < 3; ++fb) acc[fa][fb] = (f32x4){0.f, 0.f, 0.f, 0.f};

#define LOADA(AR, KK)                                                         \
    {                                                                         \
        _Pragma("unroll")                                                     \
        for (int fa = 0; fa < 4; ++fa)                                        \
            AR[fa] = *reinterpret_cast<const short8v*>(                       \
                abase + (size_t)(KK) * 4096 + fa * 128);                      \
    }

#define STEP(AR, KK)                                                         \
    {                                                                         \
        short8v bfr[3];                                                       \
        _Pragma("unroll")                                                     \
        for (int fb = 0; fb < 3; ++fb)                                        \
            bfr[fb] = *reinterpret_cast<const short8v*>(                      \
                seg + (size_t)(tn0 + fb * 16 + lane16 + 4 * (KK) + g) * 8);   \
        __builtin_amdgcn_s_setprio(1);                                        \
        _Pragma("unroll")                                                     \
        for (int fa = 0; fa < 4; ++fa) {                                      \
            _Pragma("unroll")                                                 \
            for (int fb = 0; fb < 3; ++fb)                                    \
                acc[fa][fb] = __builtin_amdgcn_mfma_f32_16x16x32_bf16(        \
                    AR[fa], bfr[fb], acc[fa][fb], 0, 0, 0);                   \
        }                                                                     \
        __builtin_amdgcn_s_setprio(0);                                        \
    }

    short8v a0[4], a1[4];
    LOADA(a0, 0);
    LOADA(a1, 1);
    int k2 = 0;
#pragma unroll 1
    for (; k2 + 3 < NK2; k2 += 2) {      // k2 = 0,2,...,120; exits k2 = 122
        STEP(a0, k2);
        LOADA(a0, k2 + 2);
        STEP(a1, k2 + 1);
        LOADA(a1, k2 + 3);
    }
    STEP(a0, k2);          // 122
    LOADA(a0, k2 + 2);
    STEP(a1, k2 + 1);      // 123
    STEP(a0, k2 + 2);      // 124

#undef LOADA
#undef STEP

    // epilogue: C/D layout col=lane16 (t), row=4*g+r (co within 16)
#pragma unroll
    for (int fa = 0; fa < 4; ++fa) {
#pragma unroll
        for (int fb = 0; fb < 3; ++fb) {
            int t = t0 + tn0 + fb * 16 + lane16;
            if (t < T2) {
                int cob = co0w + fa * 16 + 4 * g;
#pragma unroll
                for (int r = 0; r < 4; ++r)
                    part[((size_t)(s * B + b) * C2 + cob + r) * T2 + t] =
                        acc[fa][fb][r];
            }
        }
    }
}

// ---------------------------------------------------------------------------
// k2b: sum 8 cin-group partials + bias, relu + maxpool(1500) -> h1[b][co]
// ---------------------------------------------------------------------------
__global__ __launch_bounds__(256) void k2b_pool(
    const float* __restrict__ part, const float* __restrict__ b2,
    float* __restrict__ h1)
{
    int bc = blockIdx.x;             // b*C2 + co
    int b = bc / C2, co = bc % C2;
    int tid = threadIdx.x;
    float m = -INFINITY;
    for (int t4 = tid; t4 < T2 / 4; t4 += 256) {
        float4 sum = {0.f, 0.f, 0.f, 0.f};
#pragma unroll
        for (int s = 0; s < S; ++s) {
            const float4* p = reinterpret_cast<const float4*>(
                part + ((size_t)(s * B + b) * C2 + co) * T2);
            float4 v = p[t4];
            sum.x += v.x; sum.y += v.y; sum.z += v.z; sum.w += v.w;
        }
        m = fmaxf(m, fmaxf(fmaxf(sum.x, sum.y), fmaxf(sum.z, sum.w)));
    }
    __shared__ float red[256];
    red[tid] = m;
    __syncthreads();
    for (int st = 128; st > 0; st >>= 1) {
        if (tid < st) red[tid] = fmaxf(red[tid], red[tid + st]);
        __syncthreads();
    }
    if (tid == 0) h1[bc] = fmaxf(red[0] + b2[co], 0.0f);
}

// ---------------------------------------------------------------------------
// k3: lin1 + relu + lin2 + softmax. One block per batch row.
// ---------------------------------------------------------------------------
__global__ __launch_bounds__(256) void k3_head(
    const float* __restrict__ h1,
    const float* __restrict__ wl1, const float* __restrict__ bl1,
    const float* __restrict__ wl2, const float* __restrict__ bl2,
    float* __restrict__ out)
{
    int b = blockIdx.x;
    int tid = threadIdx.x;
    __shared__ float xin[C2];
    __shared__ float hbuf[HID];
    __shared__ float lg[NCLS];
    if (tid < C2) xin[tid] = h1[b * C2 + tid];
    __syncthreads();
    float a = bl1[tid];
    for (int c = 0; c < C2; ++c) a = fmaf(xin[c], wl1[tid * C2 + c], a);
    hbuf[tid] = fmaxf(a, 0.0f);
    __syncthreads();
    if (tid < NCLS) {
        float lv = bl2[tid];
        for (int j = 0; j < HID; ++j) lv = fmaf(hbuf[j], wl2[tid * HID + j], lv);
        lg[tid] = lv;
    }
    __syncthreads();
    if (tid < NCLS) {
        float mx = lg[0];
        for (int i = 1; i < NCLS; ++i) mx = fmaxf(mx, lg[i]);
        float sum = 0.f;
        for (int i = 0; i < NCLS; ++i) sum += expf(lg[i] - mx);
        out[b * NCLS + tid] = expf(lg[tid] - mx) / sum;
    }
}

extern "C" void kernel_launch(void* const* d_in, const int* in_sizes, int n_in,
                              void* d_out, int out_size, void* d_ws, size_t ws_size,
                              hipStream_t stream)
{
    const int*   x   = (const int*)  d_in[0];
    const float* emb = (const float*)d_in[1];
    const float* w1  = (const float*)d_in[2];
    const float* b1  = (const float*)d_in[3];
    const float* w2  = (const float*)d_in[4];
    const float* b2  = (const float*)d_in[5];
    const float* wl1 = (const float*)d_in[6];
    const float* bl1 = (const float*)d_in[7];
    const float* wl2 = (const float*)d_in[8];
    const float* bl2 = (const float*)d_in[9];
    float* out = (float*)d_out;

    // workspace (floats): part 8*4*128*1500 = 6,144,000 | h1 512 |
    // in1T 4*8*2304*8 bf16 = 589824 | aT 8*125*4096 bf16 = 4,096,000
    float* ws   = (float*)d_ws;
    float* part = ws;
    float* h1   = ws + (size_t)S * B * C2 * T2;
    __hip_bfloat16* in1T = (__hip_bfloat16*)(h1 + 512);
    __hip_bfloat16* aT   = in1T + (size_t)B * S * TPAD * CI;

    hipLaunchKernelGGL(k_prep, dim3(NWT + NC1B), dim3(256), 0, stream,
                       x, emb, w1, b1, w2, in1T, aT);
    hipLaunchKernelGGL(k2_mfma, dim3(512), dim3(256), 0, stream, in1T, aT, part);
    hipLaunchKernelGGL(k2b_pool, dim3(B * C2), dim3(256), 0, stream, part, b2, h1);
    hipLaunchKernelGGL(k3_head, dim3(B), dim3(256), 0, stream,
                       h1, wl1, bl1, wl2, bl2, out);
}